// Round 1
// baseline (236.566 us; speedup 1.0000x reference)
//
#include <hip/hip_runtime.h>
#include <hip/hip_bf16.h>

// Problem constants
#define HID 256
#define BATCH 4096
#define NBLK 8
#define BM 64

// ws layout (in bf16 elements)
#define OFF_O0   0u          // 8 x 256 x 32   (o_W0 transposed, K padded 24->32)
#define OFF_O1   65536u      // 8 x 256 x 256
#define OFF_O2   589824u
#define OFF_C0   1114112u
#define OFF_C1   1179648u
#define OFF_T0   1245184u
#define OFF_T1   1310720u
#define OFF_AL   1376256u    // a_W0[:256]  transposed
#define OFF_AR   1441792u    // a_W0[256:]  transposed
#define OFF_A1   1507328u
#define OFF_ENC  1572864u    // 8 x 4096 x 256 bf16
#define OFF_ALQ  9961472u    // a_l activations, 8 x 4096 x 256
#define OFF_ARQ  18350080u   // a_r activations

typedef short s8v __attribute__((ext_vector_type(8)));
typedef short s4v __attribute__((ext_vector_type(4)));
typedef float f4v __attribute__((ext_vector_type(4)));

__device__ __forceinline__ unsigned short f2bf(float f) {
  unsigned u = __float_as_uint(f);
  unsigned r = (u + 0x7FFFu + ((u >> 16) & 1u)) >> 16;
  return (unsigned short)r;
}
__device__ __forceinline__ float bf2f(unsigned short h) {
  return __uint_as_float(((unsigned)h) << 16);
}

// Epilogue shared by all GEMMs: bias + (optional) relu, write bf16 to
// swizzled LDS tile and/or row-major global.
__device__ __forceinline__ void gemm_epilogue(
    f4v acc[4][4], const float* bias, int act,
    unsigned short* outb, unsigned short* gout)
{
  int lane = threadIdx.x & 63;
  int w    = threadIdx.x >> 6;
  int lr = lane & 15, kh = lane >> 4;
  __syncthreads();   // all waves done reading the input LDS buffer
  #pragma unroll
  for (int nt = 0; nt < 4; nt++) {
    int col = w*64 + nt*16 + lr;
    float bv = bias ? bias[col] : 0.0f;
    #pragma unroll
    for (int mt = 0; mt < 4; mt++) {
      #pragma unroll
      for (int i = 0; i < 4; i++) {
        int row = mt*16 + kh*4 + i;            // C/D: col=lane&15, row=(lane>>4)*4+reg
        float v = acc[mt][nt][i] + bv;
        if (act) v = fmaxf(v, 0.0f);
        unsigned short hh = f2bf(v);
        if (outb) {
          int bofs = (2*col) ^ ((row & 7) << 4);  // XOR swizzle (G4)
          *(unsigned short*)((char*)outb + row*512 + bofs) = hh;
        }
        if (gout) gout[row*256 + col] = hh;
      }
    }
  }
  __syncthreads();   // output buffer ready
}

// 64x256 (swizzled LDS, bf16) @ 256x256 (WT global bf16, layout [n][k])
__device__ __forceinline__ void gemm64(
    const unsigned short* inb, const unsigned short* __restrict__ wt,
    const float* bias, int act,
    unsigned short* outb, unsigned short* gout)
{
  int lane = threadIdx.x & 63;
  int w    = threadIdx.x >> 6;
  int lr = lane & 15, kh = lane >> 4;
  f4v acc[4][4];
  #pragma unroll
  for (int a = 0; a < 4; a++)
    #pragma unroll
    for (int b = 0; b < 4; b++) acc[a][b] = (f4v){0.f,0.f,0.f,0.f};

  #pragma unroll
  for (int k0 = 0; k0 < 256; k0 += 32) {
    s8v bfrag[4];
    #pragma unroll
    for (int nt = 0; nt < 4; nt++)
      bfrag[nt] = *(const s8v*)(wt + (w*64 + nt*16 + lr)*256 + k0 + kh*8);
    #pragma unroll
    for (int mt = 0; mt < 4; mt++) {
      int row = mt*16 + lr;
      int bofs = (2*k0 + kh*16) ^ ((row & 7) << 4);
      s8v afrag = *(const s8v*)((const char*)inb + row*512 + bofs);
      #pragma unroll
      for (int nt = 0; nt < 4; nt++)
        acc[mt][nt] = __builtin_amdgcn_mfma_f32_16x16x32_bf16(afrag, bfrag[nt], acc[mt][nt], 0, 0, 0);
    }
  }
  gemm_epilogue(acc, bias, act, outb, gout);
}

// layer 0: 64x32 x tile (plain LDS, no swizzle) @ WT0 [256][32]; relu
__device__ __forceinline__ void gemm_x(
    const unsigned short* xb, const unsigned short* __restrict__ wt,
    const float* bias, unsigned short* outb)
{
  int lane = threadIdx.x & 63;
  int w    = threadIdx.x >> 6;
  int lr = lane & 15, kh = lane >> 4;
  f4v acc[4][4];
  #pragma unroll
  for (int a = 0; a < 4; a++)
    #pragma unroll
    for (int b = 0; b < 4; b++) acc[a][b] = (f4v){0.f,0.f,0.f,0.f};

  s8v bfrag[4];
  #pragma unroll
  for (int nt = 0; nt < 4; nt++)
    bfrag[nt] = *(const s8v*)(wt + (w*64 + nt*16 + lr)*32 + kh*8);
  #pragma unroll
  for (int mt = 0; mt < 4; mt++) {
    s8v afrag = *(const s8v*)(xb + (mt*16 + lr)*32 + kh*8);
    #pragma unroll
    for (int nt = 0; nt < 4; nt++)
      acc[mt][nt] = __builtin_amdgcn_mfma_f32_16x16x32_bf16(afrag, bfrag[nt], acc[mt][nt], 0, 0, 0);
  }
  gemm_epilogue(acc, bias, 1, outb, nullptr);
}

// out[(m0+row)*80 + offs] = sigmoid(dot(buf[row,:], wvec) + b2)
__device__ __forceinline__ void dot_sig(
    const unsigned short* buf, const float* __restrict__ wvec, float b2,
    float* out, int m0, int offs)
{
  int lane = threadIdx.x & 63;
  int w    = threadIdx.x >> 6;
  float4 wv = ((const float4*)wvec)[lane];   // cols 4*lane .. 4*lane+3
  #pragma unroll
  for (int rr = 0; rr < 16; rr++) {
    int row = w*16 + rr;
    int bofs = (8*lane) ^ ((row & 7) << 4);
    s4v pv = *(const s4v*)((const char*)buf + row*512 + bofs);
    float s = bf2f((unsigned short)pv[0])*wv.x + bf2f((unsigned short)pv[1])*wv.y
            + bf2f((unsigned short)pv[2])*wv.z + bf2f((unsigned short)pv[3])*wv.w;
    #pragma unroll
    for (int d = 32; d > 0; d >>= 1) s += __shfl_xor(s, d);
    if (lane == 0) out[(m0 + row)*80 + offs] = 1.0f / (1.0f + __expf(-s - b2));
  }
}

// ---------------- weight prep: fp32 -> bf16, transposed to [n][k] -------
__global__ __launch_bounds__(256) void prep_kernel(
    const float* __restrict__ oW0, const float* __restrict__ oW1,
    const float* __restrict__ oW2, const float* __restrict__ cW0,
    const float* __restrict__ cW1, const float* __restrict__ tW0,
    const float* __restrict__ tW1, const float* __restrict__ aW0,
    const float* __restrict__ aW1, unsigned short* __restrict__ ws)
{
  __shared__ float t[32][33];
  int b = blockIdx.x;
  if (b < 1472) {                       // 23 matrices of 256x256, 64 tiles each
    int m = b >> 6, tile = b & 63;
    const float* src; unsigned short* dst;
    if      (m < 8)  { src = oW1 + m*65536;       dst = ws + OFF_O1 + m*65536; }
    else if (m < 16) { src = oW2 + (m-8)*65536;   dst = ws + OFF_O2 + (m-8)*65536; }
    else if (m == 16){ src = cW0;                 dst = ws + OFF_C0; }
    else if (m == 17){ src = cW1;                 dst = ws + OFF_C1; }
    else if (m == 18){ src = tW0;                 dst = ws + OFF_T0; }
    else if (m == 19){ src = tW1;                 dst = ws + OFF_T1; }
    else if (m == 20){ src = aW1;                 dst = ws + OFF_A1; }
    else if (m == 21){ src = aW0;                 dst = ws + OFF_AL; }
    else             { src = aW0 + 65536;         dst = ws + OFF_AR; }
    int kt = tile & 7, nt = tile >> 3;
    int tx = threadIdx.x & 31, ty = threadIdx.x >> 5;
    #pragma unroll
    for (int r = 0; r < 4; r++) {
      int ky = ty*4 + r;
      t[ky][tx] = src[(kt*32 + ky)*256 + nt*32 + tx];
    }
    __syncthreads();
    #pragma unroll
    for (int r = 0; r < 4; r++) {
      int ny = ty*4 + r;
      dst[(nt*32 + ny)*256 + kt*32 + tx] = f2bf(t[tx][ny]);
    }
  } else {                              // o_W0: (8,24,256) -> (8,256,32) padded
    int idx = (b - 1472)*256 + threadIdx.x;
    int k = idx & 31, n2 = (idx >> 5) & 255, nb = idx >> 13;
    float v = (k < 24) ? oW0[(nb*24 + k)*256 + n2] : 0.0f;
    ws[OFF_O0 + idx] = f2bf(v);
  }
}

// ---------------- object encoders + a_l/a_r projections ------------------
__global__ __launch_bounds__(256) void encoder_kernel(
    const float* __restrict__ x,
    const float* __restrict__ ob0, const float* __restrict__ ob1,
    const float* __restrict__ ob2, unsigned short* __restrict__ ws)
{
  __shared__ unsigned short bufA[64*256];
  __shared__ unsigned short bufB[64*256];
  unsigned short* xb = bufB;   // alias: bufB unused until 2nd big GEMM
  int n  = blockIdx.x >> 6;
  int m0 = (blockIdx.x & 63) * 64;

  for (int t = threadIdx.x; t < 64*32; t += 256) {
    int row = t >> 5, c = t & 31;
    xb[t] = f2bf(c < 24 ? x[(m0 + row)*24 + c] : 0.0f);
  }
  __syncthreads();
  gemm_x (xb,   ws + OFF_O0 + n*8192,  ob0 + n*256, bufA);
  gemm64 (bufA, ws + OFF_O1 + n*65536, ob1 + n*256, 1, bufB, nullptr);
  gemm64 (bufB, ws + OFF_O2 + n*65536, ob2 + n*256, 0, bufA,
          ws + OFF_ENC + (unsigned)(n*4096 + m0)*256);
  gemm64 (bufA, ws + OFF_AL, nullptr, 0, nullptr,
          ws + OFF_ALQ + (unsigned)(n*4096 + m0)*256);
  gemm64 (bufA, ws + OFF_AR, nullptr, 0, nullptr,
          ws + OFF_ARQ + (unsigned)(n*4096 + m0)*256);
}

// ---------------- clear / ontable predicates -----------------------------
__global__ __launch_bounds__(256) void pred_kernel(
    const unsigned short* __restrict__ ws,
    const float* __restrict__ cb0, const float* __restrict__ cb1,
    const float* __restrict__ cW2, const float* __restrict__ cb2,
    const float* __restrict__ tb0, const float* __restrict__ tb1,
    const float* __restrict__ tW2, const float* __restrict__ tb2,
    float* __restrict__ out)
{
  __shared__ unsigned short bufA[64*256];
  __shared__ unsigned short bufB[64*256];
  int b  = blockIdx.x;
  int p  = b >> 9;            // 0=clear, 1=ontable
  int n  = (b >> 6) & 7;
  int m0 = (b & 63) * 64;
  const unsigned short* encp = ws + OFF_ENC + (unsigned)(n*4096 + m0)*256;

  for (int t = threadIdx.x; t < 64*32; t += 256) {
    int row = t >> 5, chunk = t & 31;
    s8v v = *(const s8v*)(encp + row*256 + chunk*8);
    int bofs = (chunk*16) ^ ((row & 7) << 4);
    *(s8v*)((char*)bufA + row*512 + bofs) = v;
  }
  __syncthreads();
  const unsigned short* W0 = ws + (p ? OFF_T0 : OFF_C0);
  const unsigned short* W1 = ws + (p ? OFF_T1 : OFF_C1);
  const float* b0 = p ? tb0 : cb0;
  const float* b1 = p ? tb1 : cb1;
  const float* W2 = p ? tW2 : cW2;
  float b2 = p ? tb2[0] : cb2[0];
  gemm64(bufA, W0, b0, 1, bufB, nullptr);
  gemm64(bufB, W1, b1, 1, bufA, nullptr);
  dot_sig(bufA, W2, b2, out, m0, n*10 + 8 + p);
}

// ---------------- AonB over all 64 (i,j) pairs ---------------------------
__global__ __launch_bounds__(256) void pair_kernel(
    const unsigned short* __restrict__ ws,
    const float* __restrict__ ab0, const float* __restrict__ ab1,
    const float* __restrict__ aW2, const float* __restrict__ ab2,
    float* __restrict__ out)
{
  __shared__ unsigned short bufA[64*256];
  __shared__ unsigned short bufB[64*256];
  int b    = blockIdx.x;
  int m0   = (b & 63) * 64;
  int pair = b >> 6;
  int i = pair >> 3, j = pair & 7;
  const unsigned short* Lp = ws + OFF_ALQ + (unsigned)(i*4096 + m0)*256;
  const unsigned short* Rp = ws + OFF_ARQ + (unsigned)(j*4096 + m0)*256;

  for (int t = threadIdx.x; t < 64*32; t += 256) {
    int row = t >> 5, chunk = t & 31;
    s8v l8 = *(const s8v*)(Lp + row*256 + chunk*8);
    s8v r8 = *(const s8v*)(Rp + row*256 + chunk*8);
    float4 ba = ((const float4*)ab0)[chunk*2];
    float4 bb = ((const float4*)ab0)[chunk*2 + 1];
    float bias[8] = {ba.x, ba.y, ba.z, ba.w, bb.x, bb.y, bb.z, bb.w};
    s8v o8;
    #pragma unroll
    for (int e = 0; e < 8; e++) {
      float v = bf2f((unsigned short)l8[e]) + bf2f((unsigned short)r8[e]) + bias[e];
      o8[e] = (short)f2bf(fmaxf(v, 0.0f));
    }
    int bofs = (chunk*16) ^ ((row & 7) << 4);
    *(s8v*)((char*)bufA + row*512 + bofs) = o8;
  }
  __syncthreads();
  gemm64(bufA, ws + OFF_A1, ab1, 1, bufB, nullptr);
  dot_sig(bufB, aW2, ab2[0], out, m0, i*10 + j);
}

extern "C" void kernel_launch(void* const* d_in, const int* in_sizes, int n_in,
                              void* d_out, int out_size, void* d_ws, size_t ws_size,
                              hipStream_t stream) {
  (void)in_sizes; (void)n_in; (void)out_size; (void)ws_size;
  const float* x   = (const float*)d_in[0];
  const float* oW0 = (const float*)d_in[1];
  const float* ob0 = (const float*)d_in[2];
  const float* oW1 = (const float*)d_in[3];
  const float* ob1 = (const float*)d_in[4];
  const float* oW2 = (const float*)d_in[5];
  const float* ob2 = (const float*)d_in[6];
  const float* cW0 = (const float*)d_in[7];
  const float* cb0 = (const float*)d_in[8];
  const float* cW1 = (const float*)d_in[9];
  const float* cb1 = (const float*)d_in[10];
  const float* cW2 = (const float*)d_in[11];
  const float* cb2 = (const float*)d_in[12];
  const float* tW0 = (const float*)d_in[13];
  const float* tb0 = (const float*)d_in[14];
  const float* tW1 = (const float*)d_in[15];
  const float* tb1 = (const float*)d_in[16];
  const float* tW2 = (const float*)d_in[17];
  const float* tb2 = (const float*)d_in[18];
  const float* aW0 = (const float*)d_in[19];
  const float* ab0 = (const float*)d_in[20];
  const float* aW1 = (const float*)d_in[21];
  const float* ab1 = (const float*)d_in[22];
  const float* aW2 = (const float*)d_in[23];
  const float* ab2 = (const float*)d_in[24];
  unsigned short* ws = (unsigned short*)d_ws;
  float* out = (float*)d_out;

  hipLaunchKernelGGL(prep_kernel, dim3(1728), dim3(256), 0, stream,
                     oW0, oW1, oW2, cW0, cW1, tW0, tW1, aW0, aW1, ws);
  hipLaunchKernelGGL(encoder_kernel, dim3(512), dim3(256), 0, stream,
                     x, ob0, ob1, ob2, ws);
  hipLaunchKernelGGL(pred_kernel, dim3(1024), dim3(256), 0, stream,
                     ws, cb0, cb1, cW2, cb2, tb0, tb1, tW2, tb2, out);
  hipLaunchKernelGGL(pair_kernel, dim3(4096), dim3(256), 0, stream,
                     ws, ab0, ab1, aW2, ab2, out);
}

// Round 2
// 185.808 us; speedup vs baseline: 1.2732x; 1.2732x over previous
//
#include <hip/hip_runtime.h>
#include <hip/hip_bf16.h>

// ws layout (in bf16 elements)
#define OFF_O0   0u          // 8 x 256 x 32   (o_W0 transposed, K padded 24->32)
#define OFF_O1   65536u      // 8 x 256 x 256
#define OFF_O2   589824u
#define OFF_C0   1114112u
#define OFF_C1   1179648u
#define OFF_T0   1245184u
#define OFF_T1   1310720u
#define OFF_AL   1376256u    // a_W0[:256]  transposed
#define OFF_AR   1441792u    // a_W0[256:]  transposed
#define OFF_A1   1507328u
#define OFF_ENC  1572864u    // 8 x 4096 x 256 bf16
#define OFF_ALQ  9961472u    // a_l activations, 8 x 4096 x 256
#define OFF_ARQ  18350080u   // a_r + ab0 activations

typedef short s8v __attribute__((ext_vector_type(8)));
typedef float f4v __attribute__((ext_vector_type(4)));

__device__ __forceinline__ unsigned short f2bf(float f) {
  unsigned u = __float_as_uint(f);
  unsigned r = (u + 0x7FFFu + ((u >> 16) & 1u)) >> 16;
  return (unsigned short)r;
}
__device__ __forceinline__ float bf2f(unsigned short h) {
  return __uint_as_float(((unsigned)h) << 16);
}

// bias + optional relu, bf16 write to swizzled LDS tile and/or row-major global.
// outb may alias the GEMM input buffer (barrier-separated in-place update).
__device__ __forceinline__ void gemm_epilogue(
    f4v acc[4][4], const float* bias, int act,
    unsigned short* outb, unsigned short* gout)
{
  int lane = threadIdx.x & 63;
  int w    = threadIdx.x >> 6;
  int lr = lane & 15, kh = lane >> 4;
  if (outb) __syncthreads();   // all waves done reading the input LDS buffer
  #pragma unroll
  for (int nt = 0; nt < 4; nt++) {
    int col = w*64 + nt*16 + lr;
    float bv = bias ? bias[col] : 0.0f;
    #pragma unroll
    for (int mt = 0; mt < 4; mt++) {
      #pragma unroll
      for (int i = 0; i < 4; i++) {
        int row = mt*16 + kh*4 + i;            // C/D: col=lane&15, row=(lane>>4)*4+reg
        float v = acc[mt][nt][i] + bv;
        if (act) v = fmaxf(v, 0.0f);
        unsigned short hh = f2bf(v);
        if (outb) {
          int bofs = (2*col) ^ ((row & 7) << 4);  // XOR swizzle (G4)
          *(unsigned short*)((char*)outb + row*512 + bofs) = hh;
        }
        if (gout) gout[row*256 + col] = hh;
      }
    }
  }
  if (outb) __syncthreads();   // output buffer ready
}

// core K loop: 64x256 (swizzled LDS bf16) @ 256x256 (global bf16, [n][k])
__device__ __forceinline__ void gemm_core(
    const unsigned short* inb, const unsigned short* __restrict__ wt,
    f4v acc[4][4])
{
  int lane = threadIdx.x & 63;
  int w    = threadIdx.x >> 6;
  int lr = lane & 15, kh = lane >> 4;
  #pragma unroll
  for (int a = 0; a < 4; a++)
    #pragma unroll
    for (int b = 0; b < 4; b++) acc[a][b] = (f4v){0.f,0.f,0.f,0.f};

  #pragma unroll
  for (int k0 = 0; k0 < 256; k0 += 32) {
    s8v bfrag[4];
    #pragma unroll
    for (int nt = 0; nt < 4; nt++)
      bfrag[nt] = *(const s8v*)(wt + (w*64 + nt*16 + lr)*256 + k0 + kh*8);
    #pragma unroll
    for (int mt = 0; mt < 4; mt++) {
      int row = mt*16 + lr;
      int bofs = (2*k0 + kh*16) ^ ((row & 7) << 4);
      s8v afrag = *(const s8v*)((const char*)inb + row*512 + bofs);
      #pragma unroll
      for (int nt = 0; nt < 4; nt++)
        acc[mt][nt] = __builtin_amdgcn_mfma_f32_16x16x32_bf16(afrag, bfrag[nt], acc[mt][nt], 0, 0, 0);
    }
  }
}

__device__ __forceinline__ void gemm64(
    const unsigned short* inb, const unsigned short* __restrict__ wt,
    const float* bias, int act, unsigned short* outb, unsigned short* gout)
{
  f4v acc[4][4];
  gemm_core(inb, wt, acc);
  gemm_epilogue(acc, bias, act, outb, gout);
}

// GEMM + fused: h2 = relu(acc + b1) (kept in f32 regs), s = h2 . w2,
// out[(m0+row)*80+offs] = sigmoid(s + b2). No LDS output tile needed.
__device__ __forceinline__ void gemm64_dot(
    const unsigned short* inb, const unsigned short* __restrict__ wt,
    const float* __restrict__ bias, const float* __restrict__ w2, float b2,
    float* __restrict__ out, int m0, int offs, float* red)
{
  int lane = threadIdx.x & 63;
  int w    = threadIdx.x >> 6;
  int lr = lane & 15, kh = lane >> 4;
  f4v acc[4][4];
  gemm_core(inb, wt, acc);

  float w2v[4], bv[4];
  #pragma unroll
  for (int nt = 0; nt < 4; nt++) {
    int col = w*64 + nt*16 + lr;
    w2v[nt] = w2[col];
    bv[nt]  = bias[col];
  }
  #pragma unroll
  for (int mt = 0; mt < 4; mt++) {
    #pragma unroll
    for (int i = 0; i < 4; i++) {
      float s = 0.0f;
      #pragma unroll
      for (int nt = 0; nt < 4; nt++)
        s += fmaxf(acc[mt][nt][i] + bv[nt], 0.0f) * w2v[nt];
      // reduce across lr (16-lane groups; xor distances < 16 stay in-group)
      s += __shfl_xor(s, 1);
      s += __shfl_xor(s, 2);
      s += __shfl_xor(s, 4);
      s += __shfl_xor(s, 8);
      if (lr == 0) red[w*64 + mt*16 + kh*4 + i] = s;
    }
  }
  __syncthreads();
  if (threadIdx.x < 64) {
    int row = threadIdx.x;
    float s = red[row] + red[64 + row] + red[128 + row] + red[192 + row];
    out[(m0 + row)*80 + offs] = 1.0f / (1.0f + __expf(-s - b2));
  }
}

// layer 0: 64x32 (plain LDS) @ WT0 [256][32]; relu
__device__ __forceinline__ void gemm_x(
    const unsigned short* xb, const unsigned short* __restrict__ wt,
    const float* bias, unsigned short* outb)
{
  int lane = threadIdx.x & 63;
  int w    = threadIdx.x >> 6;
  int lr = lane & 15, kh = lane >> 4;
  f4v acc[4][4];
  #pragma unroll
  for (int a = 0; a < 4; a++)
    #pragma unroll
    for (int b = 0; b < 4; b++) acc[a][b] = (f4v){0.f,0.f,0.f,0.f};

  s8v bfrag[4];
  #pragma unroll
  for (int nt = 0; nt < 4; nt++)
    bfrag[nt] = *(const s8v*)(wt + (w*64 + nt*16 + lr)*32 + kh*8);
  #pragma unroll
  for (int mt = 0; mt < 4; mt++) {
    s8v afrag = *(const s8v*)(xb + (mt*16 + lr)*32 + kh*8);
    #pragma unroll
    for (int nt = 0; nt < 4; nt++)
      acc[mt][nt] = __builtin_amdgcn_mfma_f32_16x16x32_bf16(afrag, bfrag[nt], acc[mt][nt], 0, 0, 0);
  }
  gemm_epilogue(acc, bias, 1, outb, nullptr);
}

// ---------------- weight prep: fp32 -> bf16, transposed to [n][k] -------
__global__ __launch_bounds__(256) void prep_kernel(
    const float* __restrict__ oW0, const float* __restrict__ oW1,
    const float* __restrict__ oW2, const float* __restrict__ cW0,
    const float* __restrict__ cW1, const float* __restrict__ tW0,
    const float* __restrict__ tW1, const float* __restrict__ aW0,
    const float* __restrict__ aW1, unsigned short* __restrict__ ws)
{
  __shared__ float t[32][33];
  int b = blockIdx.x;
  if (b < 1472) {                       // 23 matrices of 256x256, 64 tiles each
    int m = b >> 6, tile = b & 63;
    const float* src; unsigned short* dst;
    if      (m < 8)  { src = oW1 + m*65536;       dst = ws + OFF_O1 + m*65536; }
    else if (m < 16) { src = oW2 + (m-8)*65536;   dst = ws + OFF_O2 + (m-8)*65536; }
    else if (m == 16){ src = cW0;                 dst = ws + OFF_C0; }
    else if (m == 17){ src = cW1;                 dst = ws + OFF_C1; }
    else if (m == 18){ src = tW0;                 dst = ws + OFF_T0; }
    else if (m == 19){ src = tW1;                 dst = ws + OFF_T1; }
    else if (m == 20){ src = aW1;                 dst = ws + OFF_A1; }
    else if (m == 21){ src = aW0;                 dst = ws + OFF_AL; }
    else             { src = aW0 + 65536;         dst = ws + OFF_AR; }
    int kt = tile & 7, nt = tile >> 3;
    int tx = threadIdx.x & 31, ty = threadIdx.x >> 5;
    #pragma unroll
    for (int r = 0; r < 4; r++) {
      int ky = ty*4 + r;
      t[ky][tx] = src[(kt*32 + ky)*256 + nt*32 + tx];
    }
    __syncthreads();
    #pragma unroll
    for (int r = 0; r < 4; r++) {
      int ny = ty*4 + r;
      dst[(nt*32 + ny)*256 + kt*32 + tx] = f2bf(t[tx][ny]);
    }
  } else {                              // o_W0: (8,24,256) -> (8,256,32) padded
    int idx = (b - 1472)*256 + threadIdx.x;
    int k = idx & 31, n2 = (idx >> 5) & 255, nb = idx >> 13;
    float v = (k < 24) ? oW0[(nb*24 + k)*256 + n2] : 0.0f;
    ws[OFF_O0 + idx] = f2bf(v);
  }
}

// ---------------- object encoders + a_l / (a_r + b0) projections ---------
__global__ __launch_bounds__(256) void encoder_kernel(
    const float* __restrict__ x,
    const float* __restrict__ ob0, const float* __restrict__ ob1,
    const float* __restrict__ ob2, const float* __restrict__ ab0,
    unsigned short* __restrict__ ws)
{
  __shared__ unsigned short buf[64*256];   // 32 KB, chained in-place
  __shared__ unsigned short xb[64*32];     // 4 KB
  int n  = blockIdx.x >> 6;
  int m0 = (blockIdx.x & 63) * 64;

  for (int t = threadIdx.x; t < 64*32; t += 256) {
    int row = t >> 5, c = t & 31;
    xb[t] = f2bf(c < 24 ? x[(m0 + row)*24 + c] : 0.0f);
  }
  __syncthreads();
  gemm_x (xb,  ws + OFF_O0 + n*8192,  ob0 + n*256, buf);
  gemm64 (buf, ws + OFF_O1 + n*65536, ob1 + n*256, 1, buf, nullptr);
  gemm64 (buf, ws + OFF_O2 + n*65536, ob2 + n*256, 0, buf,
          ws + OFF_ENC + (unsigned)(n*4096 + m0)*256);
  gemm64 (buf, ws + OFF_AL, nullptr, 0, nullptr,
          ws + OFF_ALQ + (unsigned)(n*4096 + m0)*256);
  gemm64 (buf, ws + OFF_AR, ab0, 0, nullptr,                 // fold a_b0 here
          ws + OFF_ARQ + (unsigned)(n*4096 + m0)*256);
}

// --------- fused tail: blocks [0,4096) = AonB pairs, [4096,5120) = preds --
__global__ __launch_bounds__(256) void tail_kernel(
    const unsigned short* __restrict__ ws,
    const float* __restrict__ ab1, const float* __restrict__ aW2,
    const float* __restrict__ ab2,
    const float* __restrict__ cb0, const float* __restrict__ cb1,
    const float* __restrict__ cW2, const float* __restrict__ cb2,
    const float* __restrict__ tb0, const float* __restrict__ tb1,
    const float* __restrict__ tW2, const float* __restrict__ tb2,
    float* __restrict__ out)
{
  __shared__ unsigned short bufA[64*256];  // 32 KB
  __shared__ float red[256];               // 1 KB cross-wave dot reduce
  int b = blockIdx.x;
  if (b < 4096) {
    // ---- AonB(i,j) over a 64-row batch chunk ----
    int m0   = (b & 63) * 64;
    int pair = b >> 6;
    int i = pair >> 3, j = pair & 7;
    const unsigned short* Lp = ws + OFF_ALQ + (unsigned)(i*4096 + m0)*256;
    const unsigned short* Rp = ws + OFF_ARQ + (unsigned)(j*4096 + m0)*256;
    for (int t = threadIdx.x; t < 64*32; t += 256) {
      int row = t >> 5, chunk = t & 31;
      s8v l8 = *(const s8v*)(Lp + row*256 + chunk*8);
      s8v r8 = *(const s8v*)(Rp + row*256 + chunk*8);
      s8v o8;
      #pragma unroll
      for (int e = 0; e < 8; e++) {
        float v = bf2f((unsigned short)l8[e]) + bf2f((unsigned short)r8[e]);
        o8[e] = (short)f2bf(fmaxf(v, 0.0f));
      }
      int bofs = (chunk*16) ^ ((row & 7) << 4);
      *(s8v*)((char*)bufA + row*512 + bofs) = o8;
    }
    __syncthreads();
    gemm64_dot(bufA, ws + OFF_A1, ab1, aW2, ab2[0], out, m0, i*10 + j, red);
  } else {
    // ---- clear / ontable predicates ----
    int b2 = b - 4096;
    int p  = b2 >> 9;            // 0=clear, 1=ontable
    int n  = (b2 >> 6) & 7;
    int m0 = (b2 & 63) * 64;
    const unsigned short* encp = ws + OFF_ENC + (unsigned)(n*4096 + m0)*256;
    for (int t = threadIdx.x; t < 64*32; t += 256) {
      int row = t >> 5, chunk = t & 31;
      s8v v = *(const s8v*)(encp + row*256 + chunk*8);
      int bofs = (chunk*16) ^ ((row & 7) << 4);
      *(s8v*)((char*)bufA + row*512 + bofs) = v;
    }
    __syncthreads();
    const unsigned short* W0 = ws + (p ? OFF_T0 : OFF_C0);
    const unsigned short* W1 = ws + (p ? OFF_T1 : OFF_C1);
    gemm64(bufA, W0, p ? tb0 : cb0, 1, bufA, nullptr);      // in-place
    gemm64_dot(bufA, W1, p ? tb1 : cb1, p ? tW2 : cW2,
               p ? tb2[0] : cb2[0], out, m0, n*10 + 8 + p, red);
  }
}

extern "C" void kernel_launch(void* const* d_in, const int* in_sizes, int n_in,
                              void* d_out, int out_size, void* d_ws, size_t ws_size,
                              hipStream_t stream) {
  (void)in_sizes; (void)n_in; (void)out_size; (void)ws_size;
  const float* x   = (const float*)d_in[0];
  const float* oW0 = (const float*)d_in[1];
  const float* ob0 = (const float*)d_in[2];
  const float* oW1 = (const float*)d_in[3];
  const float* ob1 = (const float*)d_in[4];
  const float* oW2 = (const float*)d_in[5];
  const float* ob2 = (const float*)d_in[6];
  const float* cW0 = (const float*)d_in[7];
  const float* cb0 = (const float*)d_in[8];
  const float* cW1 = (const float*)d_in[9];
  const float* cb1 = (const float*)d_in[10];
  const float* cW2 = (const float*)d_in[11];
  const float* cb2 = (const float*)d_in[12];
  const float* tW0 = (const float*)d_in[13];
  const float* tb0 = (const float*)d_in[14];
  const float* tW1 = (const float*)d_in[15];
  const float* tb1 = (const float*)d_in[16];
  const float* tW2 = (const float*)d_in[17];
  const float* tb2 = (const float*)d_in[18];
  const float* aW0 = (const float*)d_in[19];
  const float* ab0 = (const float*)d_in[20];
  const float* aW1 = (const float*)d_in[21];
  const float* ab1 = (const float*)d_in[22];
  const float* aW2 = (const float*)d_in[23];
  const float* ab2 = (const float*)d_in[24];
  unsigned short* ws = (unsigned short*)d_ws;
  float* out = (float*)d_out;

  hipLaunchKernelGGL(prep_kernel, dim3(1728), dim3(256), 0, stream,
                     oW0, oW1, oW2, cW0, cW1, tW0, tW1, aW0, aW1, ws);
  hipLaunchKernelGGL(encoder_kernel, dim3(512), dim3(256), 0, stream,
                     x, ob0, ob1, ob2, ab0, ws);
  hipLaunchKernelGGL(tail_kernel, dim3(5120), dim3(256), 0, stream,
                     ws, ab1, aW2, ab2, cb0, cb1, cW2, cb2,
                     tb0, tb1, tW2, tb2, out);
}